// Round 1
// baseline (370.604 us; speedup 1.0000x reference)
//
#include <hip/hip_runtime.h>
#include <hip/hip_bf16.h>

// Problem constants
#define BDIM 8
#define TDIM 256
#define UDIM 64
#define HDIM 640
#define VDIM 1024
// M = B*T*U = 131072, K = 640, N = 1024

typedef __attribute__((ext_vector_type(8))) short short8;   // 8 bf16 (16B)
typedef __attribute__((ext_vector_type(4))) float f32x4;

__device__ __forceinline__ ushort f2bf(float x) {
    union { float f; unsigned int u; } v; v.f = x;
    unsigned int r = (v.u + 0x7fffu + ((v.u >> 16) & 1u)) >> 16;  // RNE
    return (ushort)r;
}

// Prep: convert W (V x H fp32, row-major [v][h]) to bf16 in workspace.
__global__ void cvt_w_kernel(const float* __restrict__ W, ushort* __restrict__ Wb) {
    int i = (blockIdx.x * 256 + threadIdx.x) * 4;   // grid sized exactly
    f32x4 w = *(const f32x4*)(W + i);
    ushort4 o;
    o.x = f2bf(w[0]); o.y = f2bf(w[1]); o.z = f2bf(w[2]); o.w = f2bf(w[3]);
    *(ushort4*)(Wb + i) = o;
}

// Main fused kernel: 128x128 output tile, BK=64, 4 waves (2x2), 16x16x32 bf16 MFMA.
// LDS layout for both A and B tiles: [row][slot] where slot = chunk ^ (row&7),
// chunk = 16B (8 bf16) unit index within the 64-wide K slice (8 chunks/row).
// B is filled by global_load_lds (linear LDS dest) from a pre-swizzled global
// source; A is computed in-register and ds_write'd at the swizzled slot.
template <bool USE_WB>
__global__ __launch_bounds__(256) void joint_gemm_kernel(
    const float* __restrict__ f,      // (B,T,H)
    const float* __restrict__ p,      // (B,U,H)
    const float* __restrict__ Wf,     // (V,H) fp32 (fallback path)
    const ushort* __restrict__ Wb,    // (V,H) bf16 (workspace path)
    const float* __restrict__ bias,   // (V)
    float* __restrict__ out)          // (B,T,U,V) = (M,V)
{
    __shared__ ushort Alds[128 * 64];  // 16 KB
    __shared__ ushort Blds[128 * 64];  // 16 KB

    const int tid  = threadIdx.x;
    const int lane = tid & 63;
    const int wave = tid >> 6;
    const int wm   = wave >> 1;        // wave row (0..1) -> 64 rows
    const int wn   = wave & 1;         // wave col (0..1) -> 64 cols

    // Bijective XCD swizzle: 8192 blocks, 8 XCDs. XCD x gets contiguous work
    // [x*1024, (x+1)*1024) = 128 consecutive mtiles x all 8 ntiles ->
    // W (1.25MB bf16) + f-slice stay resident in that XCD's 4MB L2.
    const int bid   = blockIdx.x;
    const int work  = (bid & 7) * 1024 + (bid >> 3);
    const int mtile = work >> 3;
    const int ntile = work & 7;
    const int m0 = mtile * 128;        // global flattened (b,t,u) row
    const int v0 = ntile * 128;

    const int b  = m0 >> 14;                 // / (T*U)
    const int t0 = (m0 >> 6) & (TDIM - 1);   // block covers t0, t0+1 (all u)

    const float*  fbase = f + (size_t)(b * TDIM + t0) * HDIM;  // 2 rows of f
    const float*  pbase = p + (size_t)b * UDIM * HDIM;         // 64 rows of p
    const ushort* wbbase = Wb + (size_t)v0 * HDIM;
    const float*  wfbase = Wf + (size_t)v0 * HDIM;

    f32x4 acc[4][4];
    #pragma unroll
    for (int i = 0; i < 4; ++i)
        #pragma unroll
        for (int j = 0; j < 4; ++j)
            acc[i][j] = (f32x4)0.0f;

    for (int kt = 0; kt < HDIM / 64; ++kt) {
        const int k0 = kt * 64;
        __syncthreads();   // previous iteration's LDS reads complete

        // ---- stage B tile: 128 (v) x 64 (k) bf16 = 1024 x 16B chunks ----
        if (USE_WB) {
            #pragma unroll
            for (int it = 0; it < 4; ++it) {
                const int c   = it * 256 + tid;
                const int row = c >> 3;
                const int j   = c & 7;
                // fetch the chunk that belongs at linear slot j: true chunk j^(row&7)
                const ushort* src = wbbase + row * HDIM + k0 + ((j ^ (row & 7)) << 3);
                __builtin_amdgcn_global_load_lds(
                    (const __attribute__((address_space(1))) void*)src,
                    (__attribute__((address_space(3))) void*)(&Blds[(it * 256 + wave * 64) * 8]),
                    16, 0, 0);
            }
        } else {
            #pragma unroll
            for (int it = 0; it < 4; ++it) {
                const int c   = it * 256 + tid;
                const int row = c >> 3;
                const int j   = c & 7;
                const float* wp = wfbase + row * HDIM + k0 + j * 8;
                f32x4 w0 = *(const f32x4*)wp;
                f32x4 w1 = *(const f32x4*)(wp + 4);
                short8 wv;
                #pragma unroll
                for (int e = 0; e < 4; ++e) {
                    wv[e]     = (short)f2bf(w0[e]);
                    wv[e + 4] = (short)f2bf(w1[e]);
                }
                *(short8*)(&Blds[(row * 8 + (j ^ (row & 7))) * 8]) = wv;
            }
        }

        // ---- stage A tile: 128 (m) x 64 (k), computed relu(f+p) -> bf16 ----
        #pragma unroll
        for (int it = 0; it < 4; ++it) {
            const int c   = it * 256 + tid;
            const int row = c >> 3;          // local m row: t = t0+(row>>6), u = row&63
            const int j   = c & 7;
            const float* fp_ = fbase + (row >> 6) * HDIM + k0 + j * 8;
            const float* pp_ = pbase + (row & 63) * HDIM + k0 + j * 8;
            f32x4 f0 = *(const f32x4*)fp_;
            f32x4 f1 = *(const f32x4*)(fp_ + 4);
            f32x4 p0 = *(const f32x4*)pp_;
            f32x4 p1 = *(const f32x4*)(pp_ + 4);
            short8 hv;
            #pragma unroll
            for (int e = 0; e < 4; ++e) {
                float a0 = f0[e] + p0[e]; a0 = fmaxf(a0, 0.0f);
                float a1 = f1[e] + p1[e]; a1 = fmaxf(a1, 0.0f);
                hv[e]     = (short)f2bf(a0);
                hv[e + 4] = (short)f2bf(a1);
            }
            *(short8*)(&Alds[(row * 8 + (j ^ (row & 7))) * 8]) = hv;
        }

        __syncthreads();   // drains vmcnt (global_load_lds) + lgkmcnt

        // ---- compute: 2 k-steps of 32, per wave 4x4 fragments ----
        #pragma unroll
        for (int ks = 0; ks < 2; ++ks) {
            short8 afr[4], bfr[4];
            #pragma unroll
            for (int mi = 0; mi < 4; ++mi) {
                const int r = wm * 64 + mi * 16 + (lane & 15);
                const int j = ks * 4 + (lane >> 4);
                afr[mi] = *(const short8*)(&Alds[(r * 8 + (j ^ (r & 7))) * 8]);
            }
            #pragma unroll
            for (int ni = 0; ni < 4; ++ni) {
                const int r = wn * 64 + ni * 16 + (lane & 15);
                const int j = ks * 4 + (lane >> 4);
                bfr[ni] = *(const short8*)(&Blds[(r * 8 + (j ^ (r & 7))) * 8]);
            }
            #pragma unroll
            for (int mi = 0; mi < 4; ++mi)
                #pragma unroll
                for (int ni = 0; ni < 4; ++ni)
                    acc[mi][ni] = __builtin_amdgcn_mfma_f32_16x16x32_bf16(
                        afr[mi], bfr[ni], acc[mi][ni], 0, 0, 0);
        }
    }

    // ---- epilogue: C/D layout col = lane&15, row = (lane>>4)*4 + reg ----
    #pragma unroll
    for (int ni = 0; ni < 4; ++ni) {
        const int col = v0 + wn * 64 + ni * 16 + (lane & 15);
        const float bv = bias[col];
        #pragma unroll
        for (int mi = 0; mi < 4; ++mi) {
            const int rbase = m0 + wm * 64 + mi * 16 + ((lane >> 4) << 2);
            #pragma unroll
            for (int reg = 0; reg < 4; ++reg) {
                out[(size_t)(rbase + reg) * VDIM + col] = acc[mi][ni][reg] + bv;
            }
        }
    }
}

extern "C" void kernel_launch(void* const* d_in, const int* in_sizes, int n_in,
                              void* d_out, int out_size, void* d_ws, size_t ws_size,
                              hipStream_t stream) {
    const float* f    = (const float*)d_in[0];   // (8,256,640)
    const float* p    = (const float*)d_in[1];   // (8,64,640)
    const float* W    = (const float*)d_in[2];   // (1024,640)
    const float* bias = (const float*)d_in[3];   // (1024)
    float* out = (float*)d_out;                  // (8,256,64,1024) fp32

    const int grid = (131072 / 128) * (VDIM / 128);  // 8192 blocks

    const size_t wb_bytes = (size_t)VDIM * HDIM * sizeof(ushort);
    if (ws_size >= wb_bytes) {
        ushort* Wb = (ushort*)d_ws;
        // 655360 elems / (256 threads * 4 per thread) = 640 blocks, exact.
        cvt_w_kernel<<<640, 256, 0, stream>>>(W, Wb);
        joint_gemm_kernel<true><<<grid, 256, 0, stream>>>(f, p, W, Wb, bias, out);
    } else {
        joint_gemm_kernel<false><<<grid, 256, 0, stream>>>(f, p, W, nullptr, bias, out);
    }
}